// Round 17
// baseline (63.847 us; speedup 1.0000x reference)
//
#include <hip/hip_runtime.h>
#include <math.h>

#define H 1024
#define W 1024
#define OH 1016
#define OW 1016
#define BH 8           // output rows per band; 127 bands, 1016 = 8*127 EXACT (no tail)
#define NBANDS 127
#define NCHUNK 5       // chunks advance 248 cols; top 2 lanes = halo providers
#define CSTR 248
#define NIMG 8
#define NWG (NBANDS*NCHUNK*NIMG)   // 5080 = 635*8 -> bijective XCD swizzle holds
#define EPS 1e-6f
#define EPS2 1e-12f    // (vv<EPS) <=> (vx*vy<EPS2)
#define INV25 (1.0f/25.0f)

// R17 = R15 coop structure at BH=8: trade per-wave amortization (+23% loads/
// row from the 34-load prologue) for 2x grid TLP (5080 one-wave blocks = ~20
// waves/CU available vs 10). Rationale: 16 rounds show time is controlled by
// resident-wave count, not VALU/L1/LDS/instrs (R15 cut L1 2.4x: flat; R16
// batched waits: worse). R2 (32 waves/CU avail) is the only config that
// showed ~36% occupancy. BH=8 also makes every band exactly valid
// (127*8=1016): no tail break, no slide guards, full unroll, static ring
// slots (s = (it+4)%5 compile-time).
// Keeps: coop float4 loads + shfl halos (R15), rsq finalize, XCD swizzle,
// per-lane float4 LDS ring (read-own-before-write-own => ordered), chunk
// stride 248 w/ store guard, launch_bounds(64,2).
// Sentinels: WRITE must stay 96774 KB (spill); conflicts ~0.

__device__ __forceinline__ float4 ld4(const float* p){ return *reinterpret_cast<const float4*>(p); }
__device__ __forceinline__ void st4(float* p, float4 v){ *reinterpret_cast<float4*>(p) = v; }

__global__ __launch_bounds__(64, 2)
void yiq_gngc_b8(const float* __restrict__ x, const float* __restrict__ y,
                 float* __restrict__ out, long long Nper)
{
    __shared__ __align__(16) float4 ring[5][2][64];   // 10240 B, per-lane float4
    const int t = (int)threadIdx.x;

    // ---- XCD-aware bijective swizzle (NWG = 635*8) ----
    const int wg  = (int)blockIdx.x;
    const int nid = (wg & 7) * (NWG / 8) + (wg >> 3);
    const int band  = nid % NBANDS;
    const int rest  = nid / NBANDS;        // 0..39
    const int chunk = rest % NCHUNK;
    const int b     = rest / NCHUNK;       // image 0..7

    const int jc = chunk * CSTR;
    const int j0 = jc + 4 * t;                         // logical cols j0..j0+3
    const int j0L = (j0 > W - 4) ? (W - 4) : j0;       // load clamp (chunk4 tail)
    const bool dostore = (t <= 61) && (j0 <= OW - 4);  // lanes 62,63 = halo-only
    const int i0 = band * BH;                          // 0..1008
    const float* xb = x + (size_t)b * (H * W) + j0L;
    const float* yb = y + (size_t)b * (H * W) + j0L;

    float csx[4], csy[4];
    float cp1[8], cp2[8], cp3[8];
    #pragma unroll
    for (int k = 0; k < 4; ++k) { csx[k] = 0.f; csy[k] = 0.f; }
    #pragma unroll
    for (int k = 0; k < 8; ++k) { cp1[k] = 0.f; cp2[k] = 0.f; cp3[k] = 0.f; }

    // ---- initial input column sums over rows i0..i0+4 ----
    #pragma unroll
    for (int r = 0; r < 5; ++r) {
        float4 vx = ld4(xb + (size_t)(i0 + r) * W);
        float4 vy = ld4(yb + (size_t)(i0 + r) * W);
        csx[0] += vx.x; csx[1] += vx.y; csx[2] += vx.z; csx[3] += vx.w;
        csy[0] += vy.x; csy[1] += vy.y; csy[2] += vy.z; csy[3] += vy.w;
    }

    // ---- zero ring slot 4 (the "row -1" subtracted at it=0) ----
    {
        float4 z = make_float4(0.f, 0.f, 0.f, 0.f);
        ring[4][0][t] = z; ring[4][1][t] = z;
    }

    // dx/dy from cs + shfl halo (verified R15). dn[k] = dx at col j0+k.
#define COMPUTE_D(dn, cs, c4)                                              \
    {                                                                      \
        float w4 = __shfl_down(cs[0], 1), w5 = __shfl_down(cs[1], 1);      \
        float w6 = __shfl_down(cs[2], 1), w7 = __shfl_down(cs[3], 1);      \
        float ce2 = __shfl_down(c4.x, 1), ce3 = __shfl_down(c4.y, 1);      \
        float m = cs[1] + cs[2] + cs[3];                                   \
        dn[0] = c4.z - (cs[0] + m + w4) * INV25;                           \
        dn[1] = c4.w - (m + w4 + w5) * INV25;                              \
        dn[2] = ce2 - (cs[2] + cs[3] + w4 + w5 + w6) * INV25;              \
        dn[3] = ce3 - (cs[3] + w4 + w5 + w6 + w7) * INV25;                 \
    }

    // ---- prime dx/dy rows i0..i0+3 into ring slots 0..3; accumulate cp ----
    #pragma unroll
    for (int pr = 0; pr < 4; ++pr) {
        float4 xc = ld4(xb + (size_t)(i0 + pr + 2) * W);
        float4 yc = ld4(yb + (size_t)(i0 + pr + 2) * W);
        float4 nx = ld4(xb + (size_t)(i0 + pr + 5) * W);
        float4 ox = ld4(xb + (size_t)(i0 + pr) * W);
        float4 ny = ld4(yb + (size_t)(i0 + pr + 5) * W);
        float4 oy = ld4(yb + (size_t)(i0 + pr) * W);

        float dxn[4], dyn[4];
        COMPUTE_D(dxn, csx, xc);
        COMPUTE_D(dyn, csy, yc);
        float dhx[4], dhy[4];
        #pragma unroll
        for (int m = 0; m < 4; ++m) { dhx[m] = __shfl_down(dxn[m], 1); dhy[m] = __shfl_down(dyn[m], 1); }

        ring[pr][0][t] = make_float4(dxn[0], dxn[1], dxn[2], dxn[3]);
        ring[pr][1][t] = make_float4(dyn[0], dyn[1], dyn[2], dyn[3]);

        #pragma unroll
        for (int k = 0; k < 4; ++k) {
            cp1[k] += dxn[k] * dyn[k];  cp1[4 + k] += dhx[k] * dhy[k];
            cp2[k] += dxn[k] * dxn[k];  cp2[4 + k] += dhx[k] * dhx[k];
            cp3[k] += dyn[k] * dyn[k];  cp3[4 + k] += dhy[k] * dhy[k];
        }
        // slide cs: add row i0+pr+5, drop row i0+pr
        csx[0] += nx.x - ox.x; csx[1] += nx.y - ox.y; csx[2] += nx.z - ox.z; csx[3] += nx.w - ox.w;
        csy[0] += ny.x - oy.x; csy[1] += ny.y - oy.y; csy[2] += ny.z - oy.z; csy[3] += ny.w - oy.w;
    }

    float* ob = out + (size_t)b * ((size_t)OH * OW) + j0;

    // ---- main loop: output rows i0..i0+7 (fully unrolled, static slots) ----
    #pragma unroll
    for (int it = 0; it < BH; ++it) {
        const int i = i0 + it;
        const int s = (it + 4) % 5;                   // compile-time ring slot
        const bool slide = (it < BH - 1);             // compile-time

        // batched loads (center i+6 <=1021; slide rows i+9 <=1022, i+4)
        float4 xc = ld4(xb + (size_t)(i + 6) * W);
        float4 yc = ld4(yb + (size_t)(i + 6) * W);
        float4 nx, ox, ny, oy;
        if (slide) {
            nx = ld4(xb + (size_t)(i + 9) * W);
            ox = ld4(xb + (size_t)(i + 4) * W);
            ny = ld4(yb + (size_t)(i + 9) * W);
            oy = ld4(yb + (size_t)(i + 4) * W);
        }

        // old dx/dy (row i-1): own 4 from ring (read-before-write, same lane
        // same address -> ordered), halo via shfl (lane63 garbage unstored)
        float4 orx = ring[s][0][t];
        float4 ory = ring[s][1][t];
        float ohx0 = __shfl_down(orx.x, 1), ohx1 = __shfl_down(orx.y, 1);
        float ohx2 = __shfl_down(orx.z, 1), ohx3 = __shfl_down(orx.w, 1);
        float ohy0 = __shfl_down(ory.x, 1), ohy1 = __shfl_down(ory.y, 1);
        float ohy2 = __shfl_down(ory.z, 1), ohy3 = __shfl_down(ory.w, 1);

        // new dx/dy row i+4
        float dxn[4], dyn[4];
        COMPUTE_D(dxn, csx, xc);
        COMPUTE_D(dyn, csy, yc);
        float dhx[4], dhy[4];
        #pragma unroll
        for (int m = 0; m < 4; ++m) { dhx[m] = __shfl_down(dxn[m], 1); dhy[m] = __shfl_down(dyn[m], 1); }

        ring[s][0][t] = make_float4(dxn[0], dxn[1], dxn[2], dxn[3]);
        ring[s][1][t] = make_float4(dyn[0], dyn[1], dyn[2], dyn[3]);

        // slide product column sums: + new row, - old row
        float odx[8] = {orx.x, orx.y, orx.z, orx.w, ohx0, ohx1, ohx2, ohx3};
        float ody[8] = {ory.x, ory.y, ory.z, ory.w, ohy0, ohy1, ohy2, ohy3};
        float ndx[8] = {dxn[0], dxn[1], dxn[2], dxn[3], dhx[0], dhx[1], dhx[2], dhx[3]};
        float ndy[8] = {dyn[0], dyn[1], dyn[2], dyn[3], dhy[0], dhy[1], dhy[2], dhy[3]};
        #pragma unroll
        for (int k = 0; k < 8; ++k) {
            cp1[k] += ndx[k] * ndy[k] - odx[k] * ody[k];
            cp2[k] += ndx[k] * ndx[k] - odx[k] * odx[k];
            cp3[k] += ndy[k] * ndy[k] - ody[k] * ody[k];
        }

        // finalize output row i, cols j0..j0+3 (rsq path)
        if (dostore) {
            float co[4], vv[4], cc[4];
            #pragma unroll
            for (int q = 0; q < 4; ++q) {
                float c_ = (cp1[q] + cp1[q+1] + cp1[q+2] + cp1[q+3] + cp1[q+4]) * INV25;
                float vx = (cp2[q] + cp2[q+1] + cp2[q+2] + cp2[q+3] + cp2[q+4]) * INV25;
                float vy = (cp3[q] + cp3[q+1] + cp3[q+2] + cp3[q+3] + cp3[q+4]) * INV25;
                float sp = vx * vy;
                bool lo  = sp < EPS2;
                float r  = __builtin_amdgcn_rsqf(sp);
                float cr = c_ * r;
                cr = cr < 0.f ? 0.f : (cr > 1.f ? 1.f : cr);
                co[q] = lo ? 0.f : cr;
                vv[q] = lo ? EPS : sp * r;
                cc[q] = lo ? 0.f : c_;
            }
            float* o = ob + (size_t)i * OW;
            st4(o,            make_float4(co[0], co[1], co[2], co[3]));
            st4(o + Nper,     make_float4(vv[0], vv[1], vv[2], vv[3]));
            st4(o + 2 * Nper, make_float4(cc[0], cc[1], cc[2], cc[3]));
        }

        // slide input column sums
        if (slide) {
            csx[0] += nx.x - ox.x; csx[1] += nx.y - ox.y; csx[2] += nx.z - ox.z; csx[3] += nx.w - ox.w;
            csy[0] += ny.x - oy.x; csy[1] += ny.y - oy.y; csy[2] += ny.z - oy.z; csy[3] += ny.w - oy.w;
        }
    }
}

extern "C" void kernel_launch(void* const* d_in, const int* in_sizes, int n_in,
                              void* d_out, int out_size, void* d_ws, size_t ws_size,
                              hipStream_t stream) {
    const float* x = (const float*)d_in[0];
    const float* y = (const float*)d_in[1];
    // mask (d_in[2]) unused by the reference's channels==1 path
    float* out = (float*)d_out;
    const long long Nper = (long long)out_size / 3;   // elements per output array
    yiq_gngc_b8<<<dim3(NWG), dim3(64), 0, stream>>>(x, y, out, Nper);
}

// Round 18
// 55.896 us; speedup vs baseline: 1.1422x; 1.1422x over previous
//
#include <hip/hip_runtime.h>
#include <math.h>

#define H 1024
#define W 1024
#define OH 1016
#define OW 1016
#define BH 16          // output rows per band; 64 bands (last has 8 valid rows)
#define NBANDS 64
#define NCHUNK 5       // chunks advance 248 cols; top 2 lanes = halo providers
#define CSTR 248
#define NIMG 8
#define NWG (NBANDS*NCHUNK*NIMG)   // 2560, divisible by 8 (bijective XCD swizzle)
#define EPS 1e-6f
#define EPS2 1e-12f
#define INV25 (1.0f/25.0f)

// R18: ONE global load round per iteration (was 3).
//  - cs via per-lane running prefix P: cs = P(it+8) - P(it+3). Pold comes
//    from a depth-6 LDS ring where each iter READS slot (it+3)%6 then WRITES
//    P(it+9) to the SAME slot -- same-lane same-address => DS program order
//    guarantees it (the R8/R14/R15-proven pattern). Kills the old-row load.
//  - center row i+6 from a depth-3 raw ring: read slot it%3 (row it+6,
//    written 3 iters ago) then write row it+9 to the SAME slot. Kills the
//    center load. Unlike R10/R11, lanes write only their OWN disjoint float4
//    (coop layout) -> no cross-lane alias -> NO fences.
// Per iter: 2 global loads (x,y new row) + 12 conflict-free b128 DS ops.
// Prologue: rows rel 0..8 loaded once each (9 rounds vs 17).
// Precision: P spans <=25 rows of N(0,1) -> err ~1e-6 << 4.4e-2 threshold.
// Keeps: BH=16 + tail break, coop shfl halos, rsq finalize, XCD swizzle,
// dx-ring, chunk stride 248 + store guard, launch_bounds(64,2).
// Sentinels: WRITE must stay 96774 KB (spill); conflicts ~0.

__device__ __forceinline__ float4 ld4(const float* p){ return *reinterpret_cast<const float4*>(p); }
__device__ __forceinline__ void st4(float* p, float4 v){ *reinterpret_cast<float4*>(p) = v; }
__device__ __forceinline__ float4 f4add(float4 a, float4 b){
    return make_float4(a.x+b.x, a.y+b.y, a.z+b.z, a.w+b.w);
}

__global__ __launch_bounds__(64, 2)
void yiq_gngc_pfx(const float* __restrict__ x, const float* __restrict__ y,
                  float* __restrict__ out, long long Nper)
{
    __shared__ __align__(16) float4 dring[5][2][64];   // 10240 B dx/dy ring
    __shared__ __align__(16) float4 pring[6][2][64];   // 12288 B prefix ring
    __shared__ __align__(16) float4 rring[3][2][64];   //  6144 B raw row ring
    const int t = (int)threadIdx.x;

    // ---- XCD-aware bijective swizzle (NWG % 8 == 0) ----
    const int wg  = (int)blockIdx.x;
    const int nid = (wg & 7) * (NWG / 8) + (wg >> 3);
    const int band  = nid % NBANDS;
    const int rest  = nid / NBANDS;
    const int chunk = rest % NCHUNK;
    const int b     = rest / NCHUNK;       // image 0..7

    const int jc = chunk * CSTR;
    const int j0 = jc + 4 * t;
    const int j0L = (j0 > W - 4) ? (W - 4) : j0;       // load clamp (chunk4 tail)
    const bool dostore = (t <= 61) && (j0 <= OW - 4);  // lanes 62,63 halo-only
    const int i0 = band * BH;                          // 0..1008
    const float* xb = x + (size_t)b * (H * W) + j0L;
    const float* yb = y + (size_t)b * (H * W) + j0L;

    float4 Px = make_float4(0.f, 0.f, 0.f, 0.f);       // prefix over rows rel 0..r
    float4 Py = make_float4(0.f, 0.f, 0.f, 0.f);
    float cp1[8], cp2[8], cp3[8];
    #pragma unroll
    for (int k = 0; k < 8; ++k) { cp1[k] = 0.f; cp2[k] = 0.f; cp3[k] = 0.f; }

    // dn[k] = d at col j0+k from cs[] + center c4 + shfl halos (R15-verified)
#define COMPUTE_D(dn, cs, c4)                                              \
    {                                                                      \
        float w4 = __shfl_down(cs[0], 1), w5 = __shfl_down(cs[1], 1);      \
        float w6 = __shfl_down(cs[2], 1), w7 = __shfl_down(cs[3], 1);      \
        float ce2 = __shfl_down(c4.x, 1), ce3 = __shfl_down(c4.y, 1);      \
        float m = cs[1] + cs[2] + cs[3];                                   \
        dn[0] = c4.z - (cs[0] + m + w4) * INV25;                           \
        dn[1] = c4.w - (m + w4 + w5) * INV25;                              \
        dn[2] = ce2 - (cs[2] + cs[3] + w4 + w5 + w6) * INV25;              \
        dn[3] = ce3 - (cs[3] + w4 + w5 + w6 + w7) * INV25;                 \
    }

    // ---- zero dring slot 4 (the "row -1" subtracted at it=0) ----
    {
        float4 z = make_float4(0.f, 0.f, 0.f, 0.f);
        dring[4][0][t] = z; dring[4][1][t] = z;
    }

    // ---- prologue: load rows rel 0..3 (build P + rings) ----
    #pragma unroll
    for (int r = 0; r < 4; ++r) {
        float4 vx = ld4(xb + (size_t)(i0 + r) * W);
        float4 vy = ld4(yb + (size_t)(i0 + r) * W);
        Px = f4add(Px, vx); Py = f4add(Py, vy);
        pring[r][0][t] = Px; pring[r][1][t] = Py;      // slot r (r<6)
        rring[r % 3][0][t] = vx; rring[r % 3][1][t] = vy;
    }

    // ---- prologue: rows rel 4..7, each followed by prime step m=r-4 ----
    // prime m computes dx-row rel m: cs = P(m+4)-P(m-1), center = raw rel m+2
    #pragma unroll
    for (int r = 4; r < 8; ++r) {
        float4 vx = ld4(xb + (size_t)(i0 + r) * W);
        float4 vy = ld4(yb + (size_t)(i0 + r) * W);
        Px = f4add(Px, vx); Py = f4add(Py, vy);
        pring[r % 6][0][t] = Px; pring[r % 6][1][t] = Py;
        rring[r % 3][0][t] = vx; rring[r % 3][1][t] = vy;

        const int m = r - 4;
        float4 cx = rring[(m + 2) % 3][0][t];
        float4 cy = rring[(m + 2) % 3][1][t];
        float4 pox, poy;
        if (m == 0) { pox = make_float4(0.f,0.f,0.f,0.f); poy = pox; }
        else        { pox = pring[m - 1][0][t]; poy = pring[m - 1][1][t]; }
        float csx[4] = {Px.x - pox.x, Px.y - pox.y, Px.z - pox.z, Px.w - pox.w};
        float csy[4] = {Py.x - poy.x, Py.y - poy.y, Py.z - poy.z, Py.w - poy.w};

        float dxn[4], dyn[4];
        COMPUTE_D(dxn, csx, cx);
        COMPUTE_D(dyn, csy, cy);
        float dhx[4], dhy[4];
        #pragma unroll
        for (int q = 0; q < 4; ++q) { dhx[q] = __shfl_down(dxn[q], 1); dhy[q] = __shfl_down(dyn[q], 1); }

        dring[m][0][t] = make_float4(dxn[0], dxn[1], dxn[2], dxn[3]);
        dring[m][1][t] = make_float4(dyn[0], dyn[1], dyn[2], dyn[3]);

        #pragma unroll
        for (int k = 0; k < 4; ++k) {
            cp1[k] += dxn[k] * dyn[k];  cp1[4 + k] += dhx[k] * dhy[k];
            cp2[k] += dxn[k] * dxn[k];  cp2[4 + k] += dhx[k] * dhx[k];
            cp3[k] += dyn[k] * dyn[k];  cp3[4 + k] += dhy[k] * dhy[k];
        }
    }

    // ---- prologue: row rel 8 (P now = P(8); raw slot 2 = rel 8) ----
    {
        float4 vx = ld4(xb + (size_t)(i0 + 8) * W);
        float4 vy = ld4(yb + (size_t)(i0 + 8) * W);
        Px = f4add(Px, vx); Py = f4add(Py, vy);
        pring[8 % 6][0][t] = Px; pring[8 % 6][1][t] = Py;
        rring[8 % 3][0][t] = vx; rring[8 % 3][1][t] = vy;
    }

    float* ob = out + (size_t)b * ((size_t)OH * OW) + j0;

    // ---- main loop: output rows i0..i0+BH-1 (tail band breaks at OH) ----
    // invariants at iter it: register P = P(it+8); pring[(it+3)%6] = P(it+3);
    // rring[it%3] = raw row rel it+6; dring[(it+4)%5] = dx/dy row rel it-1.
    #pragma unroll 4
    for (int it = 0; it < BH; ++it) {
        const int i = i0 + it;
        if (i >= OH) break;                            // block-uniform (tail band)
        const bool slide = (it < BH - 1) && (i < OH - 1);
        const int sp = (it + 3) % 6;
        const int sr = it % 3;
        const int s  = (it + 4) % 5;

        // the ONLY global loads: new row rel it+9 (max abs 1023)
        float4 nx, ny;
        if (slide) {
            nx = ld4(xb + (size_t)(i + 9) * W);
            ny = ld4(yb + (size_t)(i + 9) * W);
        }

        // LDS reads (before the same-slot writes below -> ordered per lane)
        float4 pox = pring[sp][0][t], poy = pring[sp][1][t];   // P(it+3)
        float4 cx  = rring[sr][0][t], cy  = rring[sr][1][t];   // raw rel it+6
        float4 orx = dring[s][0][t],  ory = dring[s][1][t];    // dx/dy rel it-1

        float csx[4] = {Px.x - pox.x, Px.y - pox.y, Px.z - pox.z, Px.w - pox.w};
        float csy[4] = {Py.x - poy.x, Py.y - poy.y, Py.z - poy.z, Py.w - poy.w};

        float ohx0 = __shfl_down(orx.x, 1), ohx1 = __shfl_down(orx.y, 1);
        float ohx2 = __shfl_down(orx.z, 1), ohx3 = __shfl_down(orx.w, 1);
        float ohy0 = __shfl_down(ory.x, 1), ohy1 = __shfl_down(ory.y, 1);
        float ohy2 = __shfl_down(ory.z, 1), ohy3 = __shfl_down(ory.w, 1);

        // new dx/dy row rel it+4
        float dxn[4], dyn[4];
        COMPUTE_D(dxn, csx, cx);
        COMPUTE_D(dyn, csy, cy);
        float dhx[4], dhy[4];
        #pragma unroll
        for (int q = 0; q < 4; ++q) { dhx[q] = __shfl_down(dxn[q], 1); dhy[q] = __shfl_down(dyn[q], 1); }

        dring[s][0][t] = make_float4(dxn[0], dxn[1], dxn[2], dxn[3]);
        dring[s][1][t] = make_float4(dyn[0], dyn[1], dyn[2], dyn[3]);

        // slide product column sums
        float odx[8] = {orx.x, orx.y, orx.z, orx.w, ohx0, ohx1, ohx2, ohx3};
        float ody[8] = {ory.x, ory.y, ory.z, ory.w, ohy0, ohy1, ohy2, ohy3};
        float ndx[8] = {dxn[0], dxn[1], dxn[2], dxn[3], dhx[0], dhx[1], dhx[2], dhx[3]};
        float ndy[8] = {dyn[0], dyn[1], dyn[2], dyn[3], dhy[0], dhy[1], dhy[2], dhy[3]};
        #pragma unroll
        for (int k = 0; k < 8; ++k) {
            cp1[k] += ndx[k] * ndy[k] - odx[k] * ody[k];
            cp2[k] += ndx[k] * ndx[k] - odx[k] * odx[k];
            cp3[k] += ndy[k] * ndy[k] - ody[k] * ody[k];
        }

        // finalize output row i (rsq path)
        if (dostore) {
            float co[4], vv[4], cc[4];
            #pragma unroll
            for (int q = 0; q < 4; ++q) {
                float c_ = (cp1[q] + cp1[q+1] + cp1[q+2] + cp1[q+3] + cp1[q+4]) * INV25;
                float vx = (cp2[q] + cp2[q+1] + cp2[q+2] + cp2[q+3] + cp2[q+4]) * INV25;
                float vy = (cp3[q] + cp3[q+1] + cp3[q+2] + cp3[q+3] + cp3[q+4]) * INV25;
                float sq = vx * vy;
                bool lo  = sq < EPS2;
                float rr = __builtin_amdgcn_rsqf(sq);
                float cr = c_ * rr;
                cr = cr < 0.f ? 0.f : (cr > 1.f ? 1.f : cr);
                co[q] = lo ? 0.f : cr;
                vv[q] = lo ? EPS : sq * rr;
                cc[q] = lo ? 0.f : c_;
            }
            float* o = ob + (size_t)i * OW;
            st4(o,            make_float4(co[0], co[1], co[2], co[3]));
            st4(o + Nper,     make_float4(vv[0], vv[1], vv[2], vv[3]));
            st4(o + 2 * Nper, make_float4(cc[0], cc[1], cc[2], cc[3]));
        }

        // prefix update + same-slot ring writes (AFTER the reads above)
        if (slide) {
            Px = f4add(Px, nx); Py = f4add(Py, ny);    // P(it+9)
            pring[sp][0][t] = Px; pring[sp][1][t] = Py;
            rring[sr][0][t] = nx; rring[sr][1][t] = ny;
        }
    }
}

extern "C" void kernel_launch(void* const* d_in, const int* in_sizes, int n_in,
                              void* d_out, int out_size, void* d_ws, size_t ws_size,
                              hipStream_t stream) {
    const float* x = (const float*)d_in[0];
    const float* y = (const float*)d_in[1];
    // mask (d_in[2]) unused by the reference's channels==1 path
    float* out = (float*)d_out;
    const long long Nper = (long long)out_size / 3;   // elements per output array
    yiq_gngc_pfx<<<dim3(NWG), dim3(64), 0, stream>>>(x, y, out, Nper);
}